// Round 1
// baseline (97.107 us; speedup 1.0000x reference)
//
#include <hip/hip_runtime.h>

// Problem constants (from reference): B=32, L=128, D=48, R=64
#define PB 32
#define PL 128
#define PD 48
#define PR 64

// Async global->LDS, 16B per lane, linear (wave-uniform base + lane*16) dst.
#define GLDS(gsrc, ldst)                                                      \
    __builtin_amdgcn_global_load_lds(                                         \
        (const __attribute__((address_space(1))) void*)(gsrc),                \
        (__attribute__((address_space(3))) void*)(ldst), 16, 0, 0)

// Register-tiled 4x2 (4 b's x 2 r's per block), grid = 8*32 = 256 blocks,
// 384 threads (6 waves, 1 block/CU). tid -> lg = tid/12 (L-group 0..31),
// dq = tid%12 (d-quad).
//
// R6 change: w_t was the only non-coalesced stream (each lane read 16B out
// of an 80B record -> ~80 cache lines touched per instruction vs 16 for the
// coalesced input loads; ~70% of per-CU L1 line traffic). Now the block's
// contiguous per-l-step w_t chunk (2 r x 32 l x 48 d x 5 = 2x30720B) is
// staged into LDS via global_load_lds (coalesced, zero-VGPR), and threads
// read their 20 floats with 5x ds_read_b128 at 80B lane stride (start bank
// = 20*tid mod 32: lanes 0..7 cover all 32 banks disjointly -> conflict-free).
// The staging LDS region is aliased with the part/part2 reduction buffers
// (used only after the l-loop), guarded by an extra barrier.
__device__ __forceinline__ void compute4(
    const float4 x4, const float4 t4, const float4 m4, const float4 dt4,
    const float4 p4, const float* __restrict__ w20, const float4 bt4,
    const float4 wv4, const float ar, const float refr, float4& acc)
{
    const float xs[4]  = {x4.x,  x4.y,  x4.z,  x4.w};
    const float ts[4]  = {t4.x,  t4.y,  t4.z,  t4.w};
    const float ms[4]  = {m4.x,  m4.y,  m4.z,  m4.w};
    const float dts[4] = {dt4.x, dt4.y, dt4.z, dt4.w};
    const float ps[4]  = {p4.x,  p4.y,  p4.z,  p4.w};
    const float bts[4] = {bt4.x, bt4.y, bt4.z, bt4.w};
    const float wvs[4] = {wv4.x, wv4.y, wv4.z, wv4.w};
    float a[4] = {acc.x, acc.y, acc.z, acc.w};
    #pragma unroll
    for (int j = 0; j < 4; ++j) {
        const float x = xs[j];
        const float dist = fabsf(ts[j] - refr);
        const float kern = __expf(-ar * dist);
        float inten = x * kern;
        inten = inten > 0.0f ? inten : 0.0f;
        float h = w20[j*5 + 0] * x
                + w20[j*5 + 1] * inten
                + w20[j*5 + 2] * ms[j]
                + w20[j*5 + 3] * dts[j]
                + w20[j*5 + 4] * ps[j]
                + 5.0f * bts[j];              // b_t broadcast over 5-axis
        h = h > 0.0f ? h : 0.0f;
        a[j] += wvs[j] * h;
    }
    acc = make_float4(a[0], a[1], a[2], a[3]);
}

__global__ __launch_bounds__(384) void alnn_kernel(
    const float* __restrict__ X,
    const float* __restrict__ T,
    const float* __restrict__ M,
    const float* __restrict__ DT,
    const float* __restrict__ P,
    const float* __restrict__ alpha,
    const float* __restrict__ w_t,
    const float* __restrict__ b_t,
    const float* __restrict__ w_v,
    const float* __restrict__ b_v,
    float* __restrict__ out)
{
    // 61440 B LDS, time-aliased:
    //   during l-loop : w_t stage  [r0: 7680 floats][r1: 7680 floats]
    //   after  l-loop : part (32*97 float4) + part2 (4*97 float4) = 55872 B
    __shared__ __align__(16) float smem[15360];

    const int bid = blockIdx.x;
    const int rrb = bid & 31;       // r-tile index 0..31
    const int bbb = bid >> 5;       // b-tile index 0..7
    const int r0 = rrb * 2;
    const int b0 = bbb * 4;
    const int tid = threadIdx.x;
    const int lg = tid / 12;        // 0..31
    const int dq = tid - lg * 12;   // 0..11

    const float ar0 = fmaxf(alpha[r0], 0.0f);
    const float ar1 = fmaxf(alpha[r0 + 1], 0.0f);
    const float refr0 = 48.0f * (float)r0 / 63.0f;        // linspace(0,48,64)
    const float refr1 = 48.0f * (float)(r0 + 1) / 63.0f;

    int io = b0 * (PL * PD) + lg * PD + dq * 4;            // X/T/M/DT/P, b0
    int ws = r0 * (PL * PD * 5) + tid * 4;                 // w_t staging src
    int vo = r0 * (PL * PD) + lg * PD + dq * 4;            // b_t/w_v, r0

    float4 acc[4][2];
    #pragma unroll
    for (int bi = 0; bi < 4; ++bi)
        #pragma unroll
        for (int ri = 0; ri < 2; ++ri)
            acc[bi][ri] = make_float4(0.f, 0.f, 0.f, 0.f);

    // per-thread LDS read base: addr = tid*80B  (lg*240 + dq*20 floats)
    const float* wl0 = smem + lg * 240 + dq * 20;
    const float* wl1 = wl0 + 7680;

    #pragma unroll 1
    for (int li = 0; li < 4; ++li) {
        __syncthreads();   // prior iteration's LDS w-reads done before overwrite

        // stage w_t chunk for this l-step: 2 x 30720 B, fully coalesced,
        // zero-VGPR (10 global_load_lds_dwordx4 per thread)
        #pragma unroll
        for (int k = 0; k < 5; ++k) {
            GLDS(w_t + ws + k * 1536,          smem + tid * 4 + k * 1536);
            GLDS(w_t + ws + 30720 + k * 1536,  smem + 7680 + tid * 4 + k * 1536);
        }

        // inputs for b0..b0+3 (l = li*32 + lg) — overlap with staging latency
        float4 x4[4], t4[4], m4[4], dt4[4], p4[4];
        #pragma unroll
        for (int bi = 0; bi < 4; ++bi) {
            const int o = io + bi * (PL * PD);
            x4[bi]  = *(const float4*)(X  + o);
            t4[bi]  = *(const float4*)(T  + o);
            m4[bi]  = *(const float4*)(M  + o);
            dt4[bi] = *(const float4*)(DT + o);
            p4[bi]  = *(const float4*)(P  + o);
        }
        const float4 bt0 = *(const float4*)(b_t + vo);
        const float4 wv0 = *(const float4*)(w_v + vo);
        const float4 bt1 = *(const float4*)(b_t + vo + PL * PD);
        const float4 wv1 = *(const float4*)(w_v + vo + PL * PD);

        __syncthreads();   // staging drained (vmcnt(0) before s_barrier)

        // w_t for r0, r1: 5x ds_read_b128 each, conflict-free 80B stride
        float w0[20], w1[20];
        #pragma unroll
        for (int q = 0; q < 5; ++q) {
            *(float4*)(w0 + q * 4) = *(const float4*)(wl0 + q * 4);
            *(float4*)(w1 + q * 4) = *(const float4*)(wl1 + q * 4);
        }

        #pragma unroll
        for (int bi = 0; bi < 4; ++bi) {
            compute4(x4[bi], t4[bi], m4[bi], dt4[bi], p4[bi], w0, bt0, wv0,
                     ar0, refr0, acc[bi][0]);
            compute4(x4[bi], t4[bi], m4[bi], dt4[bi], p4[bi], w1, bt1, wv1,
                     ar1, refr1, acc[bi][1]);
        }

        io += 32 * PD;        // l advances by 32
        ws += 32 * PD * 5;
        vo += 32 * PD;
    }

    __syncthreads();   // last LDS w-reads complete before aliasing as 'part'

    float4* part  = reinterpret_cast<float4*>(smem);   // [32][97]
    float4* part2 = part + 32 * 97;                    // [4][97]

    // stage partials: o = bi*24 + ri*12 + dq (row padded 96 -> 97)
    #pragma unroll
    for (int bi = 0; bi < 4; ++bi)
        #pragma unroll
        for (int ri = 0; ri < 2; ++ri)
            part[lg * 97 + bi * 24 + ri * 12 + dq] = acc[bi][ri];
    __syncthreads();

    // stage-1 reduce: 384 threads, each sums 8 of the 32 L-groups
    {
        const int q = tid / 96;         // 0..3
        const int o = tid - q * 96;     // 0..95
        float4 s = part[(q * 8) * 97 + o];
        #pragma unroll
        for (int g = 1; g < 8; ++g) {
            const float4 v = part[(q * 8 + g) * 97 + o];
            s.x += v.x; s.y += v.y; s.z += v.z; s.w += v.w;
        }
        part2[q * 97 + o] = s;
    }
    __syncthreads();

    // stage-2: combine 4 partials + bias + relu + store
    if (tid < 96) {
        const int o = tid;
        const int bi = o / 24;             // 0..3
        const int ri = (o - bi * 24) / 12; // 0..1
        const int dqo = o - bi * 24 - ri * 12;
        float4 s = part2[o];
        #pragma unroll
        for (int g = 1; g < 4; ++g) {
            const float4 v = part2[g * 97 + o];
            s.x += v.x; s.y += v.y; s.z += v.z; s.w += v.w;
        }
        const int r = r0 + ri;
        const int b = b0 + bi;
        const float4 bv4 = *(const float4*)(b_v + r * PD + dqo * 4);
        s.x = fmaxf(s.x + 128.0f * bv4.x, 0.0f);   // b_v broadcast over L
        s.y = fmaxf(s.y + 128.0f * bv4.y, 0.0f);
        s.z = fmaxf(s.z + 128.0f * bv4.z, 0.0f);
        s.w = fmaxf(s.w + 128.0f * bv4.w, 0.0f);
        *(float4*)(out + b * (PR * PD) + r * PD + dqo * 4) = s;
    }
}

extern "C" void kernel_launch(void* const* d_in, const int* in_sizes, int n_in,
                              void* d_out, int out_size, void* d_ws, size_t ws_size,
                              hipStream_t stream) {
    // setup_inputs() order: X, T, M, DT, P, alpha, w_t, b_t, w_v, b_v (all f32)
    const float* X     = (const float*)d_in[0];
    const float* T     = (const float*)d_in[1];
    const float* M     = (const float*)d_in[2];
    const float* DT    = (const float*)d_in[3];
    const float* P     = (const float*)d_in[4];
    const float* alpha = (const float*)d_in[5];
    const float* w_t   = (const float*)d_in[6];
    const float* b_t   = (const float*)d_in[7];
    const float* w_v   = (const float*)d_in[8];
    const float* b_v   = (const float*)d_in[9];
    float* out = (float*)d_out;

    alnn_kernel<<<256, 384, 0, stream>>>(X, T, M, DT, P, alpha, w_t, b_t, w_v, b_v, out);
}

// Round 2
// 93.911 us; speedup vs baseline: 1.0340x; 1.0340x over previous
//
#include <hip/hip_runtime.h>

// Problem constants (from reference): B=32, L=128, D=48, R=64
#define PB 32
#define PL 128
#define PD 48
#define PR 64

// Async global->LDS, 16B per lane, linear (wave-uniform base + lane*16) dst.
#define GLDS(gsrc, ldst)                                                      \
    __builtin_amdgcn_global_load_lds(                                         \
        (const __attribute__((address_space(1))) void*)(gsrc),                \
        (__attribute__((address_space(3))) void*)(ldst), 16, 0, 0)

// R7: pipelined LDS staging of w_t. R6 showed that __syncthreads (vmcnt(0)
// drain) around per-step staging SERIALIZES the loop (+~5us vs R5). Now the
// l-step is split into two r-phases (30720B w_t chunk each, double-buffered
// in 2x7680 floats of LDS), and the phase barrier is a raw s_barrier with
// counted vmcnt(5): the 5 global_load_lds for the NEXT phase stay in flight
// across the barrier and complete under ~1100 cy of compute. Only the last
// phase drains to 0. One barrier per phase (8 total) instead of 2 per l-step.
// vmcnt proof: at each barrier, in-flight = {<=24 input loads} + {5 next-stage
// GLDS, newest}; current stage's 5 GLDS are the oldest -> vmcnt(5) retires
// them. "memory" clobber pins GLDS before / ds_read after the barrier.
__device__ __forceinline__ void compute4(
    const float4 x4, const float4 t4, const float4 m4, const float4 dt4,
    const float4 p4, const float* __restrict__ w20, const float4 bt4,
    const float4 wv4, const float ar, const float refr, float4& acc)
{
    const float xs[4]  = {x4.x,  x4.y,  x4.z,  x4.w};
    const float ts[4]  = {t4.x,  t4.y,  t4.z,  t4.w};
    const float ms[4]  = {m4.x,  m4.y,  m4.z,  m4.w};
    const float dts[4] = {dt4.x, dt4.y, dt4.z, dt4.w};
    const float ps[4]  = {p4.x,  p4.y,  p4.z,  p4.w};
    const float bts[4] = {bt4.x, bt4.y, bt4.z, bt4.w};
    const float wvs[4] = {wv4.x, wv4.y, wv4.z, wv4.w};
    float a[4] = {acc.x, acc.y, acc.z, acc.w};
    #pragma unroll
    for (int j = 0; j < 4; ++j) {
        const float x = xs[j];
        const float dist = fabsf(ts[j] - refr);
        const float kern = __expf(-ar * dist);
        float inten = x * kern;
        inten = inten > 0.0f ? inten : 0.0f;
        float h = w20[j*5 + 0] * x
                + w20[j*5 + 1] * inten
                + w20[j*5 + 2] * ms[j]
                + w20[j*5 + 3] * dts[j]
                + w20[j*5 + 4] * ps[j]
                + 5.0f * bts[j];              // b_t broadcast over 5-axis
        h = h > 0.0f ? h : 0.0f;
        a[j] += wvs[j] * h;
    }
    acc = make_float4(a[0], a[1], a[2], a[3]);
}

__global__ __launch_bounds__(384) void alnn_kernel(
    const float* __restrict__ X,
    const float* __restrict__ T,
    const float* __restrict__ M,
    const float* __restrict__ DT,
    const float* __restrict__ P,
    const float* __restrict__ alpha,
    const float* __restrict__ w_t,
    const float* __restrict__ b_t,
    const float* __restrict__ w_v,
    const float* __restrict__ b_v,
    float* __restrict__ out)
{
    // 61440 B LDS, time-aliased:
    //   during l-loop : w_t stage buf0 [7680 floats] | buf1 [7680 floats]
    //   after  l-loop : part (32*97 f4) + part2 (4*97 f4) = 13968 floats
    __shared__ __align__(16) float smem[15360];

    const int bid = blockIdx.x;
    const int rrb = bid & 31;       // r-tile index 0..31
    const int bbb = bid >> 5;       // b-tile index 0..7
    const int r0 = rrb * 2;
    const int b0 = bbb * 4;
    const int tid = threadIdx.x;
    const int lg = tid / 12;        // 0..31
    const int dq = tid - lg * 12;   // 0..11

    const float ar0 = fmaxf(alpha[r0], 0.0f);
    const float ar1 = fmaxf(alpha[r0 + 1], 0.0f);
    const float refr0 = 48.0f * (float)r0 / 63.0f;        // linspace(0,48,64)
    const float refr1 = 48.0f * (float)(r0 + 1) / 63.0f;

    int io = b0 * (PL * PD) + lg * PD + dq * 4;            // X/T/M/DT/P, b0
    int vo = r0 * (PL * PD) + lg * PD + dq * 4;            // b_t/w_v, r0
    int wbase = r0 * 30720;                                // w_t chunk base (floats)
    const int tso = tid * 4;                               // staging lane offset

    float4 acc[4][2];
    #pragma unroll
    for (int bi = 0; bi < 4; ++bi)
        #pragma unroll
        for (int ri = 0; ri < 2; ++ri)
            acc[bi][ri] = make_float4(0.f, 0.f, 0.f, 0.f);

    // per-thread LDS read base: addr = tid*80B within a 30720B buffer
    const float* wl0 = smem + lg * 240 + dq * 20;          // buf0 (even stages)
    const float* wl1 = wl0 + 7680;                         // buf1 (odd stages)

    // prologue: stage (li=0, r0) into buf0 — 5 GLDS, fully coalesced
    #pragma unroll
    for (int k = 0; k < 5; ++k)
        GLDS(w_t + wbase + tso + k * 1536, smem + tso + k * 1536);

    #pragma unroll 1
    for (int li = 0; li < 4; ++li) {
        // inputs for b0..b0+3 (l = li*32 + lg) — 24 coalesced loads
        float4 x4[4], t4[4], m4[4], dt4[4], p4[4];
        #pragma unroll
        for (int bi = 0; bi < 4; ++bi) {
            const int o = io + bi * (PL * PD);
            x4[bi]  = *(const float4*)(X  + o);
            t4[bi]  = *(const float4*)(T  + o);
            m4[bi]  = *(const float4*)(M  + o);
            dt4[bi] = *(const float4*)(DT + o);
            p4[bi]  = *(const float4*)(P  + o);
        }
        const float4 bt0 = *(const float4*)(b_t + vo);
        const float4 wv0 = *(const float4*)(w_v + vo);
        const float4 bt1 = *(const float4*)(b_t + vo + PL * PD);
        const float4 wv1 = *(const float4*)(w_v + vo + PL * PD);

        // ---- phase r0 (even stage, compute from buf0) ----
        // stage next: (li, r1) into buf1 (always exists)
        #pragma unroll
        for (int k = 0; k < 5; ++k)
            GLDS(w_t + wbase + 30720 + tso + k * 1536,
                 smem + 7680 + tso + k * 1536);
        // drain current stage (oldest 5) + inputs; keep next 5 in flight
        asm volatile("s_waitcnt vmcnt(5)\n\ts_barrier" ::: "memory");
        {
            float w0[20];
            #pragma unroll
            for (int q = 0; q < 5; ++q)
                *(float4*)(w0 + q * 4) = *(const float4*)(wl0 + q * 4);
            #pragma unroll
            for (int bi = 0; bi < 4; ++bi)
                compute4(x4[bi], t4[bi], m4[bi], dt4[bi], p4[bi], w0, bt0, wv0,
                         ar0, refr0, acc[bi][0]);
        }

        // ---- phase r1 (odd stage, compute from buf1) ----
        if (li < 3) {
            // stage next: (li+1, r0) into buf0
            #pragma unroll
            for (int k = 0; k < 5; ++k)
                GLDS(w_t + wbase + 7680 + tso + k * 1536,
                     smem + tso + k * 1536);
            asm volatile("s_waitcnt vmcnt(5)\n\ts_barrier" ::: "memory");
        } else {
            // final stage: nothing in flight behind it — full drain
            asm volatile("s_waitcnt vmcnt(0)\n\ts_barrier" ::: "memory");
        }
        {
            float w1[20];
            #pragma unroll
            for (int q = 0; q < 5; ++q)
                *(float4*)(w1 + q * 4) = *(const float4*)(wl1 + q * 4);
            #pragma unroll
            for (int bi = 0; bi < 4; ++bi)
                compute4(x4[bi], t4[bi], m4[bi], dt4[bi], p4[bi], w1, bt1, wv1,
                         ar1, refr1, acc[bi][1]);
        }

        io += 32 * PD;        // l advances by 32
        vo += 32 * PD;
        wbase += 7680;
    }

    __syncthreads();   // all waves' LDS w-reads complete before aliasing

    float4* part  = reinterpret_cast<float4*>(smem);   // [32][97]
    float4* part2 = part + 32 * 97;                    // [4][97]

    // stage partials: o = bi*24 + ri*12 + dq (row padded 96 -> 97)
    #pragma unroll
    for (int bi = 0; bi < 4; ++bi)
        #pragma unroll
        for (int ri = 0; ri < 2; ++ri)
            part[lg * 97 + bi * 24 + ri * 12 + dq] = acc[bi][ri];
    __syncthreads();

    // stage-1 reduce: 384 threads, each sums 8 of the 32 L-groups
    {
        const int q = tid / 96;         // 0..3
        const int o = tid - q * 96;     // 0..95
        float4 s = part[(q * 8) * 97 + o];
        #pragma unroll
        for (int g = 1; g < 8; ++g) {
            const float4 v = part[(q * 8 + g) * 97 + o];
            s.x += v.x; s.y += v.y; s.z += v.z; s.w += v.w;
        }
        part2[q * 97 + o] = s;
    }
    __syncthreads();

    // stage-2: combine 4 partials + bias + relu + store
    if (tid < 96) {
        const int o = tid;
        const int bi = o / 24;             // 0..3
        const int ri = (o - bi * 24) / 12; // 0..1
        const int dqo = o - bi * 24 - ri * 12;
        float4 s = part2[o];
        #pragma unroll
        for (int g = 1; g < 4; ++g) {
            const float4 v = part2[g * 97 + o];
            s.x += v.x; s.y += v.y; s.z += v.z; s.w += v.w;
        }
        const int r = r0 + ri;
        const int b = b0 + bi;
        const float4 bv4 = *(const float4*)(b_v + r * PD + dqo * 4);
        s.x = fmaxf(s.x + 128.0f * bv4.x, 0.0f);   // b_v broadcast over L
        s.y = fmaxf(s.y + 128.0f * bv4.y, 0.0f);
        s.z = fmaxf(s.z + 128.0f * bv4.z, 0.0f);
        s.w = fmaxf(s.w + 128.0f * bv4.w, 0.0f);
        *(float4*)(out + b * (PR * PD) + r * PD + dqo * 4) = s;
    }
}

extern "C" void kernel_launch(void* const* d_in, const int* in_sizes, int n_in,
                              void* d_out, int out_size, void* d_ws, size_t ws_size,
                              hipStream_t stream) {
    // setup_inputs() order: X, T, M, DT, P, alpha, w_t, b_t, w_v, b_v (all f32)
    const float* X     = (const float*)d_in[0];
    const float* T     = (const float*)d_in[1];
    const float* M     = (const float*)d_in[2];
    const float* DT    = (const float*)d_in[3];
    const float* P     = (const float*)d_in[4];
    const float* alpha = (const float*)d_in[5];
    const float* w_t   = (const float*)d_in[6];
    const float* b_t   = (const float*)d_in[7];
    const float* w_v   = (const float*)d_in[8];
    const float* b_v   = (const float*)d_in[9];
    float* out = (float*)d_out;

    alnn_kernel<<<256, 384, 0, stream>>>(X, T, M, DT, P, alpha, w_t, b_t, w_v, b_v, out);
}